// Round 7
// baseline (418.167 us; speedup 1.0000x reference)
//
#include <hip/hip_runtime.h>
#include <math.h>

#define TT 64
#define BB 64
#define DD 512
#define HH 512
#define G4 2048
#define OO 128

typedef unsigned short us16;
typedef __attribute__((ext_vector_type(8))) short bf16x8;
typedef __attribute__((ext_vector_type(4))) float f32x4;
typedef __attribute__((ext_vector_type(4))) unsigned u32x4;
typedef __attribute__((ext_vector_type(2))) unsigned u32x2;

__device__ __forceinline__ unsigned pk_bf16(float lo, float hi) {
  unsigned r;
  asm volatile("v_cvt_pk_bf16_f32 %0, %1, %2" : "=v"(r) : "v"(lo), "v"(hi));
  return r;
}

__device__ __forceinline__ float sigm(float v) { return 1.f / (1.f + expf(-v)); }

// coherent (LLC-direct) accesses for cross-block data
__device__ __forceinline__ u32x4 load_b128_cc(const void* p) {
  u32x4 r;
  asm volatile("global_load_dwordx4 %0, %1, off sc0 sc1" : "=v"(r) : "v"(p));
  return r;
}
__device__ __forceinline__ void store_b64_cc(void* p, u32x2 v) {
  asm volatile("global_store_dwordx2 %0, %1, off sc0 sc1" ::"v"(p), "v"(v) : "memory");
}

// ============================================================================
// Phase A: G[t,b,j] = x_t @ Wih_t^T + b_ih + b_hh   via bf16 MFMA  (unchanged)
// ============================================================================
__global__ __launch_bounds__(256) void phaseA_mfma(
    const float* __restrict__ x, const float* __restrict__ wih,
    const float* __restrict__ bih, const float* __restrict__ bhh,
    float* __restrict__ Gb) {
  __shared__ us16 xa[2][64][64];
  __shared__ us16 wbuf[2][128][64];
  const int tid = threadIdx.x;
  const int t = blockIdx.y;
  const int j0 = blockIdx.x * 128;
  const int wv = tid >> 6, lane = tid & 63;
  const int wm = wv & 1, wn = wv >> 1;
  const float* xb = x + (size_t)t * (BB * DD);
  const float* wg = wih + (size_t)t * (G4 * DD) + (size_t)j0 * DD;

  float4 xr[2][2], wr[4][2];
  int xrow[2], xc[2], wrow[4], wc[4];
#pragma unroll
  for (int i = 0; i < 2; i++) { int cid = tid + i * 256; xrow[i] = cid >> 3; xc[i] = cid & 7; }
#pragma unroll
  for (int i = 0; i < 4; i++) { int cid = tid + i * 256; wrow[i] = cid >> 3; wc[i] = cid & 7; }

  auto loadx = [&](int k0) {
#pragma unroll
    for (int i = 0; i < 2; i++) {
      const float* p = xb + xrow[i] * DD + k0 + xc[i] * 8;
      xr[i][0] = *(const float4*)p; xr[i][1] = *(const float4*)(p + 4);
    }
  };
  auto loadw = [&](int k0) {
#pragma unroll
    for (int i = 0; i < 4; i++) {
      const float* p = wg + (size_t)wrow[i] * DD + k0 + wc[i] * 8;
      wr[i][0] = *(const float4*)p; wr[i][1] = *(const float4*)(p + 4);
    }
  };
  auto store = [&](int buf) {
#pragma unroll
    for (int i = 0; i < 2; i++) {
      uint4 u;
      u.x = pk_bf16(xr[i][0].x, xr[i][0].y); u.y = pk_bf16(xr[i][0].z, xr[i][0].w);
      u.z = pk_bf16(xr[i][1].x, xr[i][1].y); u.w = pk_bf16(xr[i][1].z, xr[i][1].w);
      int p = xc[i] ^ (xrow[i] & 7);
      *(uint4*)&xa[buf][xrow[i]][p * 8] = u;
    }
#pragma unroll
    for (int i = 0; i < 4; i++) {
      uint4 u;
      u.x = pk_bf16(wr[i][0].x, wr[i][0].y); u.y = pk_bf16(wr[i][0].z, wr[i][0].w);
      u.z = pk_bf16(wr[i][1].x, wr[i][1].y); u.w = pk_bf16(wr[i][1].z, wr[i][1].w);
      int p = wc[i] ^ (wrow[i] & 7);
      *(uint4*)&wbuf[buf][wrow[i]][p * 8] = u;
    }
  };

  loadx(0); loadw(0); store(0);
  __syncthreads();

  f32x4 zero = {0.f, 0.f, 0.f, 0.f};
  f32x4 acc[2][4];
#pragma unroll
  for (int mt = 0; mt < 2; mt++)
#pragma unroll
    for (int nt = 0; nt < 4; nt++) acc[mt][nt] = zero;

  for (int s = 0; s < 8; s++) {
    const int nb = s & 1;
    if (s < 7) { loadx((s + 1) * 64); loadw((s + 1) * 64); }
#pragma unroll
    for (int ks = 0; ks < 2; ks++) {
      const int cc = ks * 4 + (lane >> 4);
      bf16x8 a[2], b[4];
#pragma unroll
      for (int mt = 0; mt < 2; mt++) {
        int r = wm * 32 + mt * 16 + (lane & 15);
        a[mt] = *(const bf16x8*)&xa[nb][r][(cc ^ (r & 7)) * 8];
      }
#pragma unroll
      for (int nt = 0; nt < 4; nt++) {
        int r = wn * 64 + nt * 16 + (lane & 15);
        b[nt] = *(const bf16x8*)&wbuf[nb][r][(cc ^ (r & 7)) * 8];
      }
#pragma unroll
      for (int mt = 0; mt < 2; mt++)
#pragma unroll
        for (int nt = 0; nt < 4; nt++)
          acc[mt][nt] = __builtin_amdgcn_mfma_f32_16x16x32_bf16(a[mt], b[nt], acc[mt][nt], 0, 0, 0);
    }
    __syncthreads();
    if (s < 7) store(nb ^ 1);
    __syncthreads();
  }

  float bias[4]; int jn[4];
#pragma unroll
  for (int nt = 0; nt < 4; nt++) {
    jn[nt] = j0 + wn * 64 + nt * 16 + (lane & 15);
    bias[nt] = bih[t * G4 + jn[nt]] + bhh[t * G4 + jn[nt]];
  }
#pragma unroll
  for (int mt = 0; mt < 2; mt++)
#pragma unroll
    for (int nt = 0; nt < 4; nt++)
#pragma unroll
      for (int e = 0; e < 4; e++) {
        int brow = wm * 32 + mt * 16 + (lane >> 4) * 4 + e;
        Gb[((size_t)t * BB + brow) * G4 + jn[nt]] = acc[mt][nt][e] + bias[nt];
      }
}

// ============================================================================
// Persistent LSTM stepper with WAVE SPECIALIZATION.
// 256 blocks (bh = bid&1 batch-half, ug = bid>>1 -> units ug*4..+3), 4 waves:
//   waves 0,1 (GEMM): wm=wv batch-16-half, FULL k=512 (16 MFMA, no k-reduce).
//   wave 2: epilogue (c in regs), publish h records + flag, prefetch G.
//   wave 3: W-streamer -> LDS double buffer (own vmcnt: loads cross barriers).
// h records: 8 B [4 bf16], layout rec[b][u4] so one b128 = A-frag (2 recs).
// Sync: per-producer flags (16B apart), raw s_barriers (no vmcnt drains).
// ============================================================================
__global__ __launch_bounds__(256, 1) void lstm_persist(
    const float* __restrict__ whh, const float* __restrict__ Gb,
    const int* __restrict__ lengths, char* __restrict__ hb,
    float* __restrict__ hf, unsigned* __restrict__ flags) {
  __shared__ us16 wbuf[2][16][512];  // 32 KB: bf16 W double buffer (swizzled)
  __shared__ float gm[16][36];       // gate partials [gaterow][batch32]

  const int tid = threadIdx.x, bid = blockIdx.x;
  const int bh = bid & 1, ug = bid >> 1;
  const int wv = tid >> 6, lane = tid & 63;
  const int l15 = lane & 15, klg = lane >> 4;

  // ---- wave2 state ----
  float2 gpre[4];
  auto prefG = [&](int tt) {
    const float* gbp =
        Gb + ((size_t)tt * BB + bh * 32 + (lane & 31)) * G4 + ug * 4 + ((lane >> 5) << 1);
#pragma unroll
    for (int q = 0; q < 4; q++) gpre[q] = *(const float2*)(gbp + q * 512);
  };
  float cst[2] = {0.f, 0.f};
  const int mylen = (wv == 2) ? lengths[bh * 32 + (lane & 31)] : -2;
  if (wv == 2) prefG(0);

  // ---- wave3 state ----
  float4 pfA[16], pfB[16];

  // consumer record base: rec[b = wv*16+l15][u4], 8 B each
  const char* crb0 = hb + (size_t)bh * 32768 + (size_t)(wv * 16 + l15) * 1024;

  for (int t = 0; t < TT; t++) {
    // ---------------- poll flags (GEMM waves only) ----------------
    if (wv < 2 && t > 0) {
      const unsigned tgt = (unsigned)t;
      const int pidx = (2 * (wv * 64 + lane) + bh) * 4;
      while (true) {
        unsigned f = __hip_atomic_load(&flags[pidx], __ATOMIC_RELAXED,
                                       __HIP_MEMORY_SCOPE_AGENT);
        if (__all(f >= tgt)) break;
        __builtin_amdgcn_s_sleep(1);
      }
    }
    __builtin_amdgcn_s_barrier();  // BAR-A: flags seen; W(t) in LDS; gm free
    asm volatile("" ::: "memory");

    // ---------------- GEMM (waves 0,1) ----------------
    if (wv < 2) {
      f32x4 acc = {0.f, 0.f, 0.f, 0.f};
      if (t > 0) {
        const char* rb = crb0 + (size_t)(t & 1) * 65536;
        u32x4 hfrag[16];
#pragma unroll
        for (int s = 0; s < 16; s++)
          hfrag[s] = load_b128_cc(rb + s * 64 + klg * 16);
        bf16x8 wf[16];
#pragma unroll
        for (int s = 0; s < 16; s++)
          wf[s] = *(const bf16x8*)&wbuf[t & 1][l15][((4 * s + klg) ^ (l15 & 7)) * 8];
        asm volatile("s_waitcnt vmcnt(0) lgkmcnt(0)" ::: "memory");
        __builtin_amdgcn_sched_barrier(0);
#pragma unroll
        for (int s = 0; s < 16; s++)
          acc = __builtin_amdgcn_mfma_f32_16x16x32_bf16(__builtin_bit_cast(bf16x8, hfrag[s]),
                                                        wf[s], acc, 0, 0, 0);
      }
      *(f32x4*)&gm[l15][wv * 16 + klg * 4] = acc;
      asm volatile("s_waitcnt lgkmcnt(0)" ::: "memory");
    }
    // ---------------- W-streamer: issue loads for t+1 (own vmcnt) ----------
    if (wv == 3 && t + 1 < TT) {
      const float* wt = whh + (size_t)(t + 1) * (G4 * HH);
#pragma unroll
      for (int j = 0; j < 16; j++) {
        const float* p = wt + (size_t)((j >> 2) * 512 + ug * 4 + (j & 3)) * HH + lane * 8;
        pfA[j] = *(const float4*)p;
        pfB[j] = *(const float4*)(p + 4);
      }
    }
    __builtin_amdgcn_s_barrier();  // BAR-B: gm ready
    asm volatile("" ::: "memory");

    // ---------------- epilogue (wave 2) ----------------
    if (wv == 2) {
      float2 gcur[4];
#pragma unroll
      for (int q = 0; q < 4; q++) gcur[q] = gpre[q];
      const int b = lane & 31, hi = lane >> 5;
      float hv[2];
#pragma unroll
      for (int uu = 0; uu < 2; uu++) {
        const int lu = hi * 2 + uu;
        float vi = (uu ? gcur[0].y : gcur[0].x) + gm[0 + lu][b];
        float vf = (uu ? gcur[1].y : gcur[1].x) + gm[4 + lu][b];
        float vg = (uu ? gcur[2].y : gcur[2].x) + gm[8 + lu][b];
        float vo = (uu ? gcur[3].y : gcur[3].x) + gm[12 + lu][b];
        float cn = sigm(vf) * cst[uu] + sigm(vi) * tanhf(vg);
        cst[uu] = cn;
        hv[uu] = sigm(vo) * tanhf(cn);
      }
      unsigned hw = pk_bf16(hv[0], hv[1]);
      unsigned other = __shfl_xor(hw, 32);
      if (mylen - 1 == t) {
        float2 o2; o2.x = hv[0]; o2.y = hv[1];
        *(float2*)&hf[(size_t)(bh * 32 + b) * HH + ug * 4 + hi * 2] = o2;
      }
      if (t + 1 < TT) {
        if (lane < 32) {
          u32x2 rec = {hw, other};
          store_b64_cc(hb + (size_t)((t + 1) & 1) * 65536 + (size_t)bh * 32768 +
                           (size_t)(lane * 128 + ug) * 8,
                       rec);
        }
        asm volatile("s_waitcnt vmcnt(0)" ::: "memory");
        if (lane == 0)
          __hip_atomic_store(&flags[bid * 4], (unsigned)(t + 1), __ATOMIC_RELAXED,
                             __HIP_MEMORY_SCOPE_AGENT);
        prefG(t + 1);
      }
    }
    // ---------------- W-streamer: cvt + LDS write for t+1 ----------------
    if (wv == 3 && t + 1 < TT) {
      const int sl = (t + 1) & 1;
#pragma unroll
      for (int j = 0; j < 16; j++) {
        u32x4 w;
        w.x = pk_bf16(pfA[j].x, pfA[j].y); w.y = pk_bf16(pfA[j].z, pfA[j].w);
        w.z = pk_bf16(pfB[j].x, pfB[j].y); w.w = pk_bf16(pfB[j].z, pfB[j].w);
        *(u32x4*)&wbuf[sl][j][(lane ^ (j & 7)) * 8] = w;
      }
      asm volatile("s_waitcnt lgkmcnt(0)" ::: "memory");
    }
  }
}

// ============================================================================
// Final: logits = hf @ w_ho^T + b_ho, then log_softmax
// ============================================================================
__global__ __launch_bounds__(128) void finalK(const float* __restrict__ hf,
                                              const float* __restrict__ who,
                                              const float* __restrict__ bho,
                                              float* __restrict__ out) {
  int b = blockIdx.x, o = threadIdx.x;
  const float* h = hf + b * HH;
  const float* w = who + o * HH;
  float s = bho[o];
#pragma unroll 4
  for (int k = 0; k < HH; k += 4) {
    float4 hv = *(const float4*)(h + k);
    float4 wv = *(const float4*)(w + k);
    s += hv.x * wv.x + hv.y * wv.y + hv.z * wv.z + hv.w * wv.w;
  }
  __shared__ float red[2];
  __shared__ float red2[2];
  float m = s;
#pragma unroll
  for (int msk = 32; msk; msk >>= 1) m = fmaxf(m, __shfl_xor(m, msk));
  int wave = o >> 6;
  if ((o & 63) == 0) red[wave] = m;
  __syncthreads();
  m = fmaxf(red[0], red[1]);
  float e = expf(s - m);
#pragma unroll
  for (int msk = 32; msk; msk >>= 1) e += __shfl_xor(e, msk);
  if ((o & 63) == 0) red2[wave] = e;
  __syncthreads();
  float sum = red2[0] + red2[1];
  out[b * OO + o] = (s - m) - logf(sum);
}

extern "C" void kernel_launch(void* const* d_in, const int* in_sizes, int n_in,
                              void* d_out, int out_size, void* d_ws, size_t ws_size,
                              hipStream_t stream) {
  const float* x = (const float*)d_in[0];
  const float* wih = (const float*)d_in[1];
  const float* whh = (const float*)d_in[2];
  const float* bih = (const float*)d_in[3];
  const float* bhh = (const float*)d_in[4];
  const float* who = (const float*)d_in[5];
  const float* bho = (const float*)d_in[6];
  const int* lengths = (const int*)d_in[7];
  float* out = (float*)d_out;

  char* ws = (char*)d_ws;
  float* Gb = (float*)ws;                            // 33,554,432 B
  char* hb = ws + 33554432;                          // 131,072 B (2 slots x 64 b x 128 u4 x 8 B)
  unsigned* flags = (unsigned*)(ws + 33554432 + 131072);  // 4,096 B (256 flags, 16 B apart)
  float* hf = (float*)(ws + 33554432 + 131072 + 4096);    // 131,072 B

  (void)hipMemsetAsync(flags, 0, 4096, stream);  // flags must start at 0 each launch

  phaseA_mfma<<<dim3(16, 64), 256, 0, stream>>>(x, wih, bih, bhh, Gb);
  lstm_persist<<<256, 256, 0, stream>>>(whh, Gb, lengths, hb, hf, flags);
  finalK<<<BB, 128, 0, stream>>>(hf, who, bho, out);
}